// Round 1
// baseline (310.781 us; speedup 1.0000x reference)
//
#include <hip/hip_runtime.h>
#include <hip/hip_bf16.h>
#include <cstdint>
#include <cstddef>

#define B_  2
#define Q_  256
#define KL  2048
#define D_  256
#define H_  8
#define HD_ 32
#define CH_ 256

typedef __hip_bfloat16 bf16;
typedef unsigned short ushortv8 __attribute__((ext_vector_type(8)));

__device__ __forceinline__ float b2f(unsigned short u) {
  return __uint_as_float(((unsigned int)u) << 16);
}

// out[row][c] = dot(in[row][:], W[c][:]) + bias[c]   (row = b*Q+q, c = 0..255)
__global__ __launch_bounds__(256) void proj_row(const float* __restrict__ in,
                                                const float* __restrict__ W,
                                                const float* __restrict__ bias,
                                                float* __restrict__ out) {
  int row = blockIdx.x;
  __shared__ float r[D_];
  r[threadIdx.x] = in[(size_t)row * D_ + threadIdx.x];
  __syncthreads();
  int c = threadIdx.x;
  const float* w = W + (size_t)c * D_;
  float acc = bias[c];
#pragma unroll 8
  for (int d = 0; d < D_; ++d) acc = fmaf(r[d], w[d], acc);
  out[(size_t)row * D_ + c] = acc;
}

// kv projection: 16 image rows per block, weight-stationary, bf16 outputs
// kp/vp layout: [b][h][kk][dd]
__global__ __launch_bounds__(256) void proj_kv(const float* __restrict__ img,
                                               const float* __restrict__ Wkv,
                                               const float* __restrict__ bkv,
                                               bf16* __restrict__ kp,
                                               bf16* __restrict__ vp) {
  int blk = blockIdx.x;
  int b = blk >> 7, t0 = (blk & 127) << 4;  // 16 rows per block
  __shared__ float rows[16][D_];
  for (int i = threadIdx.x; i < 16 * D_; i += 256)
    rows[i >> 8][i & 255] = img[((size_t)b * KL + t0 + (i >> 8)) * D_ + (i & 255)];
  __syncthreads();
  int c = threadIdx.x;
  const float* w0 = Wkv + (size_t)c * D_;
  const float* w1 = Wkv + (size_t)(c + 256) * D_;
  float acc0[16], acc1[16];
  float bk = bkv[c], bv = bkv[c + 256];
#pragma unroll
  for (int r = 0; r < 16; ++r) { acc0[r] = bk; acc1[r] = bv; }
  for (int d = 0; d < D_; d += 4) {
    float4 a = *(const float4*)(w0 + d);
    float4 e = *(const float4*)(w1 + d);
#pragma unroll
    for (int r = 0; r < 16; ++r) {
      float4 xr = *(const float4*)&rows[r][d];
      acc0[r] = fmaf(xr.x, a.x, acc0[r]);
      acc0[r] = fmaf(xr.y, a.y, acc0[r]);
      acc0[r] = fmaf(xr.z, a.z, acc0[r]);
      acc0[r] = fmaf(xr.w, a.w, acc0[r]);
      acc1[r] = fmaf(xr.x, e.x, acc1[r]);
      acc1[r] = fmaf(xr.y, e.y, acc1[r]);
      acc1[r] = fmaf(xr.z, e.z, acc1[r]);
      acc1[r] = fmaf(xr.w, e.w, acc1[r]);
    }
  }
  int h = c >> 5, dd = c & 31;
#pragma unroll
  for (int r = 0; r < 16; ++r) {
    size_t idx = ((size_t)(b * H_ + h) * KL + t0 + r) * HD_ + dd;
    kp[idx] = __float2bfloat16(acc0[r]);
    vp[idx] = __float2bfloat16(acc1[r]);
  }
}

// fused logits = QK^T * scale + CPB-MLP; block per (b,q); 8 kk per thread
__global__ __launch_bounds__(256) void logits_cpb(
    const float* __restrict__ qp, const bf16* __restrict__ kp,
    const float* __restrict__ rd, const float* __restrict__ W1,
    const float* __restrict__ b1, const float* __restrict__ W2,
    const float* __restrict__ b2, float* __restrict__ logits) {
  int bqi = blockIdx.x;
  int b = bqi >> 8, q = bqi & 255;
  __shared__ float qrow[D_];
  qrow[threadIdx.x] = qp[(size_t)(b * Q_ + q) * D_ + threadIdx.x];
  __syncthreads();

  // per-thread relative distances for its 8 kk positions
  float x[8], y[8];
#pragma unroll
  for (int i = 0; i < 8; ++i) {
    int kk = threadIdx.x + (i << 8);
    float2 p = *(const float2*)(rd + ((size_t)(b * Q_ + q) * KL + kk) * 2);
    x[i] = p.x; y[i] = p.y;
  }

  float acc[8][H_];
#pragma unroll
  for (int i = 0; i < 8; ++i)
#pragma unroll
    for (int h = 0; h < H_; ++h) acc[i][h] = 0.f;

  // CPB MLP: c loop runtime (uniform -> scalar weight loads), i/h unrolled
  for (int c = 0; c < CH_; ++c) {
    float w10 = W1[2 * c], w11 = W1[2 * c + 1], bb = b1[c];
    float w2[H_];
#pragma unroll
    for (int h = 0; h < H_; ++h) w2[h] = W2[h * CH_ + c];
#pragma unroll
    for (int i = 0; i < 8; ++i) {
      float z = fmaf(x[i], w10, fmaf(y[i], w11, bb));
      z = fmaxf(z, 0.0f);
#pragma unroll
      for (int h = 0; h < H_; ++h) acc[i][h] = fmaf(z, w2[h], acc[i][h]);
    }
  }

  const float scale = 0.17677669529663687f;  // 1/sqrt(32)
#pragma unroll
  for (int h = 0; h < H_; ++h) {
    float lg[8];
#pragma unroll
    for (int i = 0; i < 8; ++i) lg[i] = 0.f;
#pragma unroll
    for (int d0 = 0; d0 < HD_; d0 += 8) {
      float q8[8];
#pragma unroll
      for (int j = 0; j < 8; ++j) q8[j] = qrow[h * HD_ + d0 + j];
#pragma unroll
      for (int i = 0; i < 8; ++i) {
        int kk = threadIdx.x + (i << 8);
        ushortv8 k8 = *(const ushortv8*)((const unsigned short*)kp +
                       ((size_t)(b * H_ + h) * KL + kk) * HD_ + d0);
#pragma unroll
        for (int j = 0; j < 8; ++j) lg[i] = fmaf(q8[j], b2f(k8[j]), lg[i]);
      }
    }
    float bh2 = b2[h];
#pragma unroll
    for (int i = 0; i < 8; ++i) {
      int kk = threadIdx.x + (i << 8);
      logits[((size_t)(b * H_ + h) * Q_ + q) * KL + kk] = lg[i] * scale + acc[i][h] + bh2;
    }
  }
}

// softmax over K per (b,h,q) row; writes bf16 attn
__global__ __launch_bounds__(256) void softmax_k(const float* __restrict__ logits,
                                                 bf16* __restrict__ attn) {
  size_t r = blockIdx.x;
  const float* row = logits + r * KL;
  int t = threadIdx.x;
  float v[8];
  float m = -3.0e38f;
#pragma unroll
  for (int i = 0; i < 8; ++i) {
    v[i] = row[t + (i << 8)];
    m = fmaxf(m, v[i]);
  }
#pragma unroll
  for (int off = 32; off > 0; off >>= 1) m = fmaxf(m, __shfl_xor(m, off));
  __shared__ float redm[4];
  __shared__ float reds[4];
  int w = t >> 6, lane = t & 63;
  if (lane == 0) redm[w] = m;
  __syncthreads();
  m = fmaxf(fmaxf(redm[0], redm[1]), fmaxf(redm[2], redm[3]));
  float s = 0.f;
#pragma unroll
  for (int i = 0; i < 8; ++i) { v[i] = __expf(v[i] - m); s += v[i]; }
#pragma unroll
  for (int off = 32; off > 0; off >>= 1) s += __shfl_xor(s, off);
  if (lane == 0) reds[w] = s;
  __syncthreads();
  s = reds[0] + reds[1] + reds[2] + reds[3];
  float inv = 1.0f / s;
#pragma unroll
  for (int i = 0; i < 8; ++i)
    attn[r * KL + t + (i << 8)] = __float2bfloat16(v[i] * inv);
}

// PV: block per (b,h, 8 q-rows); thread = (r, dd); ctx layout [b][q][h*32+dd]
__global__ __launch_bounds__(256) void pv(const bf16* __restrict__ attn,
                                          const bf16* __restrict__ vp,
                                          float* __restrict__ ctx) {
  int blk = blockIdx.x;
  int qt = blk & 31, bh = blk >> 5;
  int r = threadIdx.x >> 5, dd = threadIdx.x & 31;
  int q = (qt << 3) + r;
  const unsigned short* arow =
      (const unsigned short*)attn + ((size_t)bh * Q_ + q) * KL;
  const unsigned short* vbase =
      (const unsigned short*)vp + (size_t)bh * KL * HD_ + dd;
  float acc = 0.f;
  for (int kk = 0; kk < KL; kk += 8) {
    ushortv8 a8 = *(const ushortv8*)(arow + kk);
#pragma unroll
    for (int j = 0; j < 8; ++j)
      acc = fmaf(b2f(a8[j]), b2f(vbase[(size_t)(kk + j) * HD_]), acc);
  }
  int hh = bh & 7, bb = bh >> 3;
  ctx[((size_t)bb * Q_ + q) * D_ + hh * HD_ + dd] = acc;
}

extern "C" void kernel_launch(void* const* d_in, const int* in_sizes, int n_in,
                              void* d_out, int out_size, void* d_ws, size_t ws_size,
                              hipStream_t stream) {
  const float* ent  = (const float*)d_in[0];
  const float* img  = (const float*)d_in[1];
  const float* rd   = (const float*)d_in[2];
  const float* Wq   = (const float*)d_in[3];
  const float* bq   = (const float*)d_in[4];
  const float* Wkv  = (const float*)d_in[5];
  const float* bkv  = (const float*)d_in[6];
  const float* W1   = (const float*)d_in[7];
  const float* b1   = (const float*)d_in[8];
  const float* W2   = (const float*)d_in[9];
  const float* b2   = (const float*)d_in[10];
  const float* Wo   = (const float*)d_in[11];
  const float* bo   = (const float*)d_in[12];
  float* out = (float*)d_out;

  char* ws = (char*)d_ws;
  // workspace layout (bytes)
  float* qp   = (float*)(ws + 0);          //   524,288  fp32 [b][q][c]
  bf16*  kp   = (bf16*)(ws + 524288);      // 2,097,152  bf16 [b][h][kk][dd]
  bf16*  vpp  = (bf16*)(ws + 2621440);     // 2,097,152  bf16 [b][h][kk][dd]
  float* lgts = (float*)(ws + 4718592);    // 33,554,432 fp32 [b][h][q][kk]
  bf16*  attn = (bf16*)(ws + 38273024);    // 16,777,216 bf16 [b][h][q][kk]
  float* ctx  = (float*)(ws + 55050240);   //   524,288  fp32 [b][q][c]

  proj_row<<<dim3(B_ * Q_), dim3(256), 0, stream>>>(ent, Wq, bq, qp);
  proj_kv<<<dim3(B_ * (KL / 16)), dim3(256), 0, stream>>>(img, Wkv, bkv, kp, vpp);
  logits_cpb<<<dim3(B_ * Q_), dim3(256), 0, stream>>>(qp, kp, rd, W1, b1, W2, b2, lgts);
  softmax_k<<<dim3(B_ * H_ * Q_), dim3(256), 0, stream>>>(lgts, attn);
  pv<<<dim3(B_ * H_ * (Q_ / 8)), dim3(256), 0, stream>>>(attn, vpp, ctx);
  proj_row<<<dim3(B_ * Q_), dim3(256), 0, stream>>>(ctx, Wo, bo, out);
}

// Round 2
// 195.405 us; speedup vs baseline: 1.5904x; 1.5904x over previous
//
#include <hip/hip_runtime.h>
#include <hip/hip_bf16.h>
#include <cstdint>
#include <cstddef>

#define B_  2
#define Q_  256
#define KL  2048
#define D_  256
#define H_  8
#define HD_ 32
#define CH_ 256

typedef unsigned short ushortv8 __attribute__((ext_vector_type(8)));
typedef short short8 __attribute__((ext_vector_type(8)));
typedef float f32x4 __attribute__((ext_vector_type(4)));

__device__ __forceinline__ float b2f(unsigned short u) {
  return __uint_as_float(((unsigned int)u) << 16);
}
__device__ __forceinline__ unsigned short f2b_bits(float x) {
  unsigned int u = __float_as_uint(x);
  u += 0x7FFFu + ((u >> 16) & 1u);  // RNE
  return (unsigned short)(u >> 16);
}

// out[row][c] = dot(in[row][:], W[c][:]) + bias[c]
__global__ __launch_bounds__(256) void proj_row(const float* __restrict__ in,
                                                const float* __restrict__ W,
                                                const float* __restrict__ bias,
                                                float* __restrict__ out) {
  int row = blockIdx.x;
  __shared__ float r[D_];
  r[threadIdx.x] = in[(size_t)row * D_ + threadIdx.x];
  __syncthreads();
  int c = threadIdx.x;
  const float4* w4 = (const float4*)(W + (size_t)c * D_);
  float acc = bias[c];
#pragma unroll 8
  for (int d = 0; d < D_ / 4; ++d) {
    float4 w = w4[d];
    float4 xr = *(const float4*)&r[d * 4];
    acc = fmaf(xr.x, w.x, acc);
    acc = fmaf(xr.y, w.y, acc);
    acc = fmaf(xr.z, w.z, acc);
    acc = fmaf(xr.w, w.w, acc);
  }
  out[(size_t)row * D_ + c] = acc;
}

// kv projection: kp [b][h][kk][dd] bf16; vt [b][h][dd][kk] bf16 (transposed)
__global__ __launch_bounds__(256) void proj_kv(const float* __restrict__ img,
                                               const float* __restrict__ Wkv,
                                               const float* __restrict__ bkv,
                                               unsigned short* __restrict__ kp,
                                               unsigned short* __restrict__ vt) {
  int blk = blockIdx.x;
  int b = blk >> 7, t0 = (blk & 127) << 4;  // 16 rows per block
  __shared__ float rows[16][D_];
  for (int i = threadIdx.x; i < 16 * D_; i += 256)
    rows[i >> 8][i & 255] = img[((size_t)b * KL + t0 + (i >> 8)) * D_ + (i & 255)];
  __syncthreads();
  int c = threadIdx.x;
  const float* w0 = Wkv + (size_t)c * D_;
  const float* w1 = Wkv + (size_t)(c + 256) * D_;
  float acc0[16], acc1[16];
  float bk = bkv[c], bv = bkv[c + 256];
#pragma unroll
  for (int r = 0; r < 16; ++r) { acc0[r] = bk; acc1[r] = bv; }
  for (int d = 0; d < D_; d += 4) {
    float4 a = *(const float4*)(w0 + d);
    float4 e = *(const float4*)(w1 + d);
#pragma unroll
    for (int r = 0; r < 16; ++r) {
      float4 xr = *(const float4*)&rows[r][d];
      acc0[r] = fmaf(xr.x, a.x, acc0[r]);
      acc0[r] = fmaf(xr.y, a.y, acc0[r]);
      acc0[r] = fmaf(xr.z, a.z, acc0[r]);
      acc0[r] = fmaf(xr.w, a.w, acc0[r]);
      acc1[r] = fmaf(xr.x, e.x, acc1[r]);
      acc1[r] = fmaf(xr.y, e.y, acc1[r]);
      acc1[r] = fmaf(xr.z, e.z, acc1[r]);
      acc1[r] = fmaf(xr.w, e.w, acc1[r]);
    }
  }
  int h = c >> 5, dd = c & 31;
  // K: [b][h][kk][dd], scalar stores (coalesced across dd within a row)
#pragma unroll
  for (int r = 0; r < 16; ++r)
    kp[((size_t)(b * H_ + h) * KL + t0 + r) * HD_ + dd] = f2b_bits(acc0[r]);
  // V transposed: [b][h][dd][kk], packed 16B stores
  ushortv8 p0, p1;
#pragma unroll
  for (int r = 0; r < 8; ++r) { p0[r] = f2b_bits(acc1[r]); p1[r] = f2b_bits(acc1[r + 8]); }
  unsigned short* vb = vt + ((size_t)(b * H_ + h) * HD_ + dd) * KL + t0;
  *(ushortv8*)(vb) = p0;
  *(ushortv8*)(vb + 8) = p1;
}

// fused logits = QK^T * scale + CPB-MLP; grid = B*Q*2; 4 kk/thread; bf16 out
__global__ __launch_bounds__(256) void logits_cpb(
    const float* __restrict__ qp, const unsigned short* __restrict__ kp,
    const float* __restrict__ rd, const float* __restrict__ W1,
    const float* __restrict__ b1, const float* __restrict__ W2,
    const float* __restrict__ b2, unsigned short* __restrict__ logits) {
  int half = blockIdx.x & 1, bqi = blockIdx.x >> 1;
  int b = bqi >> 8, q = bqi & 255;
  int t = threadIdx.x;
  __shared__ float qrow[D_];
  __shared__ float4 w1s[CH_];      // {W1[c][0], W1[c][1], b1[c], 0}
  __shared__ float4 w2s[CH_][2];   // W2[0..7][c]
  qrow[t] = qp[(size_t)(b * Q_ + q) * D_ + t];
  w1s[t] = make_float4(W1[2 * t], W1[2 * t + 1], b1[t], 0.f);
  float4 lo, hi;
  lo.x = W2[0 * CH_ + t]; lo.y = W2[1 * CH_ + t];
  lo.z = W2[2 * CH_ + t]; lo.w = W2[3 * CH_ + t];
  hi.x = W2[4 * CH_ + t]; hi.y = W2[5 * CH_ + t];
  hi.z = W2[6 * CH_ + t]; hi.w = W2[7 * CH_ + t];
  w2s[t][0] = lo; w2s[t][1] = hi;
  __syncthreads();

  int kkb = (half << 10) + t;  // positions kkb + i*256, i=0..3
  float x[4], y[4];
#pragma unroll
  for (int i = 0; i < 4; ++i) {
    float2 p = *(const float2*)(rd + ((size_t)(b * Q_ + q) * KL + kkb + (i << 8)) * 2);
    x[i] = p.x; y[i] = p.y;
  }

  float acc[4][H_];
#pragma unroll
  for (int i = 0; i < 4; ++i)
#pragma unroll
    for (int h = 0; h < H_; ++h) acc[i][h] = 0.f;

#pragma unroll 4
  for (int c = 0; c < CH_; ++c) {
    float4 a = w1s[c];
    float4 u0 = w2s[c][0], u1 = w2s[c][1];
#pragma unroll
    for (int i = 0; i < 4; ++i) {
      float z = fmaf(x[i], a.x, fmaf(y[i], a.y, a.z));
      z = fmaxf(z, 0.0f);
      acc[i][0] = fmaf(z, u0.x, acc[i][0]);
      acc[i][1] = fmaf(z, u0.y, acc[i][1]);
      acc[i][2] = fmaf(z, u0.z, acc[i][2]);
      acc[i][3] = fmaf(z, u0.w, acc[i][3]);
      acc[i][4] = fmaf(z, u1.x, acc[i][4]);
      acc[i][5] = fmaf(z, u1.y, acc[i][5]);
      acc[i][6] = fmaf(z, u1.z, acc[i][6]);
      acc[i][7] = fmaf(z, u1.w, acc[i][7]);
    }
  }

  const float scale = 0.17677669529663687f;  // 1/sqrt(32)
#pragma unroll
  for (int h = 0; h < H_; ++h) {
    float lg[4] = {0.f, 0.f, 0.f, 0.f};
#pragma unroll
    for (int d0 = 0; d0 < HD_; d0 += 8) {
      float q8[8];
#pragma unroll
      for (int j = 0; j < 8; ++j) q8[j] = qrow[h * HD_ + d0 + j];
#pragma unroll
      for (int i = 0; i < 4; ++i) {
        ushortv8 k8 = *(const ushortv8*)(kp +
            ((size_t)(b * H_ + h) * KL + kkb + (i << 8)) * HD_ + d0);
#pragma unroll
        for (int j = 0; j < 8; ++j) lg[i] = fmaf(q8[j], b2f(k8[j]), lg[i]);
      }
    }
    float bh2 = b2[h];
#pragma unroll
    for (int i = 0; i < 4; ++i)
      logits[((size_t)(b * H_ + h) * Q_ + q) * KL + kkb + (i << 8)] =
          f2b_bits(lg[i] * scale + acc[i][h] + bh2);
  }
}

// softmax over K per (b,h,q) row; bf16 in, bf16 out; 8 contiguous elems/thread
__global__ __launch_bounds__(256) void softmax_k(const unsigned short* __restrict__ logits,
                                                 unsigned short* __restrict__ attn) {
  size_t r = blockIdx.x;
  int t = threadIdx.x;
  ushortv8 raw = *(const ushortv8*)(logits + r * KL + t * 8);
  float v[8];
  float m = -3.0e38f;
#pragma unroll
  for (int i = 0; i < 8; ++i) { v[i] = b2f(raw[i]); m = fmaxf(m, v[i]); }
#pragma unroll
  for (int off = 32; off > 0; off >>= 1) m = fmaxf(m, __shfl_xor(m, off));
  __shared__ float redm[4];
  __shared__ float reds[4];
  int w = t >> 6, lane = t & 63;
  if (lane == 0) redm[w] = m;
  __syncthreads();
  m = fmaxf(fmaxf(redm[0], redm[1]), fmaxf(redm[2], redm[3]));
  float s = 0.f;
#pragma unroll
  for (int i = 0; i < 8; ++i) { v[i] = __expf(v[i] - m); s += v[i]; }
#pragma unroll
  for (int off = 32; off > 0; off >>= 1) s += __shfl_xor(s, off);
  if (lane == 0) reds[w] = s;
  __syncthreads();
  s = reds[0] + reds[1] + reds[2] + reds[3];
  float inv = 1.0f / s;
  ushortv8 o;
#pragma unroll
  for (int i = 0; i < 8; ++i) o[i] = f2b_bits(v[i] * inv);
  *(ushortv8*)(attn + r * KL + t * 8) = o;
}

// PV via MFMA: grid = B*H*(Q/16), 64 threads (1 wave). D[16q x 32dd].
__global__ __launch_bounds__(64) void pv_mfma(const unsigned short* __restrict__ attn,
                                              const unsigned short* __restrict__ vt,
                                              float* __restrict__ ctx) {
  int bh = blockIdx.x >> 4, qt = blockIdx.x & 15;
  int l = threadIdx.x;
  int r = l & 15, g = l >> 4;
  const short* ab = (const short*)attn + ((size_t)bh * Q_ + qt * 16 + r) * KL + g * 8;
  const short* vb0 = (const short*)vt + ((size_t)bh * HD_ + r) * KL + g * 8;
  const short* vb1 = vb0 + (size_t)16 * KL;
  f32x4 acc0 = {0.f, 0.f, 0.f, 0.f}, acc1 = {0.f, 0.f, 0.f, 0.f};
  for (int ks = 0; ks < KL; ks += 32) {
    short8 a = *(const short8*)(ab + ks);
    short8 v0 = *(const short8*)(vb0 + ks);
    short8 v1 = *(const short8*)(vb1 + ks);
    acc0 = __builtin_amdgcn_mfma_f32_16x16x32_bf16(a, v0, acc0, 0, 0, 0);
    acc1 = __builtin_amdgcn_mfma_f32_16x16x32_bf16(a, v1, acc1, 0, 0, 0);
  }
  int brow = bh >> 3, h = bh & 7;
  float* cb = ctx + ((size_t)brow * Q_ + qt * 16 + g * 4) * D_ + h * HD_;
#pragma unroll
  for (int rr = 0; rr < 4; ++rr) {
    cb[(size_t)rr * D_ + r] = acc0[rr];
    cb[(size_t)rr * D_ + 16 + r] = acc1[rr];
  }
}

extern "C" void kernel_launch(void* const* d_in, const int* in_sizes, int n_in,
                              void* d_out, int out_size, void* d_ws, size_t ws_size,
                              hipStream_t stream) {
  const float* ent  = (const float*)d_in[0];
  const float* img  = (const float*)d_in[1];
  const float* rd   = (const float*)d_in[2];
  const float* Wq   = (const float*)d_in[3];
  const float* bq   = (const float*)d_in[4];
  const float* Wkv  = (const float*)d_in[5];
  const float* bkv  = (const float*)d_in[6];
  const float* W1   = (const float*)d_in[7];
  const float* b1   = (const float*)d_in[8];
  const float* W2   = (const float*)d_in[9];
  const float* b2   = (const float*)d_in[10];
  const float* Wo   = (const float*)d_in[11];
  const float* bo   = (const float*)d_in[12];
  float* out = (float*)d_out;

  char* ws = (char*)d_ws;
  float*          qp   = (float*)(ws + 0);                  //   524,288 fp32 [b][q][c]
  unsigned short* kp   = (unsigned short*)(ws + 524288);    // 2,097,152 bf16 [b][h][kk][dd]
  unsigned short* vt   = (unsigned short*)(ws + 2621440);   // 2,097,152 bf16 [b][h][dd][kk]
  unsigned short* lgb  = (unsigned short*)(ws + 4718592);   // 16,777,216 bf16 [b][h][q][kk]
  unsigned short* attn = (unsigned short*)(ws + 21495808);  // 16,777,216 bf16 [b][h][q][kk]
  float*          ctx  = (float*)(ws + 38273024);           //   524,288 fp32 [b][q][c]

  proj_row<<<dim3(B_ * Q_), dim3(256), 0, stream>>>(ent, Wq, bq, qp);
  proj_kv<<<dim3(B_ * (KL / 16)), dim3(256), 0, stream>>>(img, Wkv, bkv, kp, vt);
  logits_cpb<<<dim3(B_ * Q_ * 2), dim3(256), 0, stream>>>(qp, kp, rd, W1, b1, W2, b2, lgb);
  softmax_k<<<dim3(B_ * H_ * Q_), dim3(256), 0, stream>>>(lgb, attn);
  pv_mfma<<<dim3(B_ * H_ * (Q_ / 16)), dim3(64), 0, stream>>>(attn, vt, ctx);
  proj_row<<<dim3(B_ * Q_), dim3(256), 0, stream>>>(ctx, Wo, bo, out);
}

// Round 3
// 158.338 us; speedup vs baseline: 1.9628x; 1.2341x over previous
//
#include <hip/hip_runtime.h>
#include <hip/hip_bf16.h>
#include <cstdint>
#include <cstddef>

#define B_  2
#define Q_  256
#define KL  2048
#define D_  256
#define H_  8
#define HD_ 32
#define CH_ 256

typedef unsigned short ushortv8 __attribute__((ext_vector_type(8)));
typedef short short8 __attribute__((ext_vector_type(8)));
typedef float f32x4 __attribute__((ext_vector_type(4)));

union U4S8 { unsigned int u[4]; short8 s; };

__device__ __forceinline__ float b2f(unsigned short u) {
  return __uint_as_float(((unsigned int)u) << 16);
}
__device__ __forceinline__ unsigned short f2b_bits(float x) {
  unsigned int u = __float_as_uint(x);
  u += 0x7FFFu + ((u >> 16) & 1u);  // RNE
  return (unsigned short)(u >> 16);
}
__device__ __forceinline__ unsigned int cvt_pk_bf16(float lo, float hi) {
  unsigned int r;
  asm("v_cvt_pk_bf16_f32 %0, %1, %2" : "=v"(r) : "v"(lo), "v"(hi));
  return r;
}

// out[row][c] = dot(in[row][:], W[c][:]) + bias[c]
__global__ __launch_bounds__(256) void proj_row(const float* __restrict__ in,
                                                const float* __restrict__ W,
                                                const float* __restrict__ bias,
                                                float* __restrict__ out) {
  int row = blockIdx.x;
  __shared__ float r[D_];
  r[threadIdx.x] = in[(size_t)row * D_ + threadIdx.x];
  __syncthreads();
  int c = threadIdx.x;
  const float4* w4 = (const float4*)(W + (size_t)c * D_);
  float acc = bias[c];
#pragma unroll 8
  for (int d = 0; d < D_ / 4; ++d) {
    float4 w = w4[d];
    float4 xr = *(const float4*)&r[d * 4];
    acc = fmaf(xr.x, w.x, acc);
    acc = fmaf(xr.y, w.y, acc);
    acc = fmaf(xr.z, w.z, acc);
    acc = fmaf(xr.w, w.w, acc);
  }
  out[(size_t)row * D_ + c] = acc;
}

// kv projection: kp [b][kk][c] bf16 (row-major); vt [b][h][dd][kk] bf16
__global__ __launch_bounds__(256) void proj_kv(const float* __restrict__ img,
                                               const float* __restrict__ Wkv,
                                               const float* __restrict__ bkv,
                                               unsigned short* __restrict__ kp,
                                               unsigned short* __restrict__ vt) {
  int blk = blockIdx.x;
  int b = blk >> 7, t0 = (blk & 127) << 4;  // 16 rows per block
  __shared__ float rows[16][D_];
  for (int i = threadIdx.x; i < 16 * D_; i += 256)
    rows[i >> 8][i & 255] = img[((size_t)b * KL + t0 + (i >> 8)) * D_ + (i & 255)];
  __syncthreads();
  int c = threadIdx.x;
  const float* w0 = Wkv + (size_t)c * D_;
  const float* w1 = Wkv + (size_t)(c + 256) * D_;
  float acc0[16], acc1[16];
  float bk = bkv[c], bv = bkv[c + 256];
#pragma unroll
  for (int r = 0; r < 16; ++r) { acc0[r] = bk; acc1[r] = bv; }
  for (int d = 0; d < D_; d += 4) {
    float4 a = *(const float4*)(w0 + d);
    float4 e = *(const float4*)(w1 + d);
#pragma unroll
    for (int r = 0; r < 16; ++r) {
      float4 xr = *(const float4*)&rows[r][d];
      acc0[r] = fmaf(xr.x, a.x, acc0[r]);
      acc0[r] = fmaf(xr.y, a.y, acc0[r]);
      acc0[r] = fmaf(xr.z, a.z, acc0[r]);
      acc0[r] = fmaf(xr.w, a.w, acc0[r]);
      acc1[r] = fmaf(xr.x, e.x, acc1[r]);
      acc1[r] = fmaf(xr.y, e.y, acc1[r]);
      acc1[r] = fmaf(xr.z, e.z, acc1[r]);
      acc1[r] = fmaf(xr.w, e.w, acc1[r]);
    }
  }
  // K: [b][kk][c] — coalesced across c
#pragma unroll
  for (int r = 0; r < 16; ++r)
    kp[((size_t)b * KL + t0 + r) * D_ + c] = f2b_bits(acc0[r]);
  // V transposed: [b][h][dd][kk], packed 16B stores
  int h = c >> 5, dd = c & 31;
  ushortv8 p0, p1;
#pragma unroll
  for (int r = 0; r < 8; ++r) { p0[r] = f2b_bits(acc1[r]); p1[r] = f2b_bits(acc1[r + 8]); }
  unsigned short* vb = vt + ((size_t)(b * H_ + h) * HD_ + dd) * KL + t0;
  *(ushortv8*)(vb) = p0;
  *(ushortv8*)(vb + 8) = p1;
}

// logits = QK^T*scale + CPB via MFMA.
// block = (b, q, kc of 256 k); 4 waves x 4 rounds x 16 k.
// Layer2: A=z[16k][256c] (computed on VALU, packed bf16), B=W2^T.
// QK:     A=Kmat[16k][256c], B=block-diag(q*scale).
__global__ __launch_bounds__(256) void logits_cpb(
    const float* __restrict__ qp, const unsigned short* __restrict__ kp,
    const float* __restrict__ rd, const float* __restrict__ W1,
    const float* __restrict__ b1, const float* __restrict__ W2,
    const float* __restrict__ b2, unsigned short* __restrict__ lgb) {
  int gid = blockIdx.x;
  int q = gid & 255, kc = (gid >> 8) & 7, b = gid >> 11;
  int t = threadIdx.x;
  __shared__ float2 w1p[CH_];
  __shared__ float b1s[CH_];
  __shared__ float qrow[D_];
  __shared__ unsigned short w2b[H_][272];  // padded vs 256 for bank spread
  __shared__ float b2s[H_];
  w1p[t] = make_float2(W1[2 * t], W1[2 * t + 1]);
  b1s[t] = b1[t];
  qrow[t] = qp[(size_t)(b * Q_ + q) * D_ + t];
#pragma unroll
  for (int h = 0; h < H_; ++h) w2b[h][t] = f2b_bits(W2[h * CH_ + t]);
  if (t < H_) b2s[t] = b2[t];
  __syncthreads();

  int l = t & 63, w = t >> 6;
  int hp = l & 15, g = l >> 4, hq = hp & 7;
  int k0 = kc * 256 + w * 64;

  // per-lane x,y for its 4 k-rows (k = k0 + r*16 + hp)
  float x[4], y[4];
#pragma unroll
  for (int r = 0; r < 4; ++r) {
    float2 p = *(const float2*)(rd + ((size_t)(b * Q_ + q) * KL + k0 + r * 16 + hp) * 2);
    x[r] = p.x; y[r] = p.y;
  }
  const float scale = 0.17677669529663687f;  // 1/sqrt(32)
  // q-fragment (nonzero only at chain step s == hp)
  unsigned int qf[4];
#pragma unroll
  for (int m = 0; m < 4; ++m)
    qf[m] = cvt_pk_bf16(qrow[hq * 32 + g * 8 + 2 * m] * scale,
                        qrow[hq * 32 + g * 8 + 2 * m + 1] * scale);

  f32x4 acc[4];
#pragma unroll
  for (int r = 0; r < 4; ++r) acc[r] = (f32x4){0.f, 0.f, 0.f, 0.f};

  const unsigned short* kpb = kp + (size_t)b * KL * D_;
#pragma unroll
  for (int s = 0; s < 8; ++s) {
    int cb = g * 8 + 32 * s;  // this lane's 8 c's for chain step s
    float2 wp[8]; float bb[8];
#pragma unroll
    for (int j = 0; j < 8; ++j) { wp[j] = w1p[cb + j]; bb[j] = b1s[cb + j]; }
    short8 w2f = *(const short8*)&w2b[hq][cb];
    U4S8 bq;
#pragma unroll
    for (int m = 0; m < 4; ++m) bq.u[m] = (hp == s) ? qf[m] : 0u;
#pragma unroll
    for (int r = 0; r < 4; ++r) {
      short8 kf = *(const short8*)(kpb + (size_t)(k0 + r * 16 + hp) * D_ + cb);
      U4S8 az;
#pragma unroll
      for (int m = 0; m < 4; ++m) {
        float z0 = fmaxf(fmaf(x[r], wp[2 * m].x, fmaf(y[r], wp[2 * m].y, bb[2 * m])), 0.f);
        float z1 = fmaxf(fmaf(x[r], wp[2 * m + 1].x, fmaf(y[r], wp[2 * m + 1].y, bb[2 * m + 1])), 0.f);
        az.u[m] = cvt_pk_bf16(z0, z1);
      }
      acc[r] = __builtin_amdgcn_mfma_f32_16x16x32_bf16(az.s, w2f, acc[r], 0, 0, 0);
      acc[r] = __builtin_amdgcn_mfma_f32_16x16x32_bf16(kf, bq.s, acc[r], 0, 0, 0);
    }
  }
  // C/D: col = l&15 (= head), row = g*4 + rr (k within round)
  if (hp < H_) {
    float bh = b2s[hp];
    unsigned short* ob = lgb + ((size_t)(b * H_ + hp) * Q_ + q) * KL + k0;
#pragma unroll
    for (int r = 0; r < 4; ++r)
#pragma unroll
      for (int rr = 0; rr < 4; ++rr)
        ob[r * 16 + g * 4 + rr] = f2b_bits(acc[r][rr] + bh);
  }
}

// fused softmax + PV: block = (b,h, 16 q-rows), 512 threads (8 waves).
// pass1: row max + exp-sum from bf16 logits; pass2: re-read logits in
// A-fragment order (L2-hot), exp in-register, MFMA against V^T; reduce
// partial PV across waves in LDS.
__global__ __launch_bounds__(512) void sm_pv(const unsigned short* __restrict__ lgb,
                                             const unsigned short* __restrict__ vt,
                                             float* __restrict__ ctx) {
  int gid = blockIdx.x;
  int qt = gid & 15, bh = gid >> 4;  // bh = b*H + h
  int t = threadIdx.x;
  __shared__ float mrow[16], srow[16];
  __shared__ float pacc[8][16][33];

  // ---- pass 1: per-row max and sum(exp) ----
  int row = t >> 5, ch = t & 31;
  const unsigned short* lr = lgb + ((size_t)bh * Q_ + qt * 16 + row) * KL;
  ushortv8 vv[8];
  float m = -3.0e38f;
#pragma unroll
  for (int i = 0; i < 8; ++i) {
    vv[i] = *(const ushortv8*)(lr + ch * 8 + i * 256);
#pragma unroll
    for (int j = 0; j < 8; ++j) m = fmaxf(m, b2f(vv[i][j]));
  }
#pragma unroll
  for (int off = 16; off > 0; off >>= 1) m = fmaxf(m, __shfl_xor(m, off));
  float s = 0.f;
#pragma unroll
  for (int i = 0; i < 8; ++i)
#pragma unroll
    for (int j = 0; j < 8; ++j) s += __expf(b2f(vv[i][j]) - m);
#pragma unroll
  for (int off = 16; off > 0; off >>= 1) s += __shfl_xor(s, off);
  if (ch == 0) { mrow[row] = m; srow[row] = 1.0f / s; }
  __syncthreads();

  // ---- pass 2: PV via MFMA; wave w covers k in [w*256, w*256+256) ----
  int l = t & 63, w = t >> 6;
  int qq = l & 15, g = l >> 4;
  float mq = mrow[qq];
  const unsigned short* lr2 = lgb + ((size_t)bh * Q_ + qt * 16 + qq) * KL + w * 256 + g * 8;
  const unsigned short* vb0 = vt + ((size_t)bh * HD_ + qq) * KL + w * 256 + g * 8;
  const unsigned short* vb1 = vb0 + (size_t)16 * KL;
  f32x4 a0 = {0.f, 0.f, 0.f, 0.f}, a1 = {0.f, 0.f, 0.f, 0.f};
#pragma unroll
  for (int step = 0; step < 8; ++step) {
    ushortv8 rawp = *(const ushortv8*)(lr2 + step * 32);
    U4S8 pa;
#pragma unroll
    for (int mI = 0; mI < 4; ++mI) {
      float p0 = __expf(b2f(rawp[2 * mI]) - mq);
      float p1 = __expf(b2f(rawp[2 * mI + 1]) - mq);
      pa.u[mI] = cvt_pk_bf16(p0, p1);
    }
    short8 v0 = *(const short8*)(vb0 + step * 32);
    short8 v1 = *(const short8*)(vb1 + step * 32);
    a0 = __builtin_amdgcn_mfma_f32_16x16x32_bf16(pa.s, v0, a0, 0, 0, 0);
    a1 = __builtin_amdgcn_mfma_f32_16x16x32_bf16(pa.s, v1, a1, 0, 0, 0);
  }
  // C/D: row (q) = g*4+rr, col (dd) = l&15
#pragma unroll
  for (int rr = 0; rr < 4; ++rr) {
    pacc[w][g * 4 + rr][qq] = a0[rr];
    pacc[w][g * 4 + rr][qq + 16] = a1[rr];
  }
  __syncthreads();

  // ---- final: sum 8 wave-partials, scale by 1/s, write ctx ----
  int qo = t >> 5, dd = t & 31;
  float sum = 0.f;
#pragma unroll
  for (int wv = 0; wv < 8; ++wv) sum += pacc[wv][qo][dd];
  int b = bh >> 3, h = bh & 7;
  ctx[((size_t)b * Q_ + qt * 16 + qo) * D_ + h * HD_ + dd] = sum * srow[qo];
}

extern "C" void kernel_launch(void* const* d_in, const int* in_sizes, int n_in,
                              void* d_out, int out_size, void* d_ws, size_t ws_size,
                              hipStream_t stream) {
  const float* ent  = (const float*)d_in[0];
  const float* img  = (const float*)d_in[1];
  const float* rd   = (const float*)d_in[2];
  const float* Wq   = (const float*)d_in[3];
  const float* bq   = (const float*)d_in[4];
  const float* Wkv  = (const float*)d_in[5];
  const float* bkv  = (const float*)d_in[6];
  const float* W1   = (const float*)d_in[7];
  const float* b1   = (const float*)d_in[8];
  const float* W2   = (const float*)d_in[9];
  const float* b2   = (const float*)d_in[10];
  const float* Wo   = (const float*)d_in[11];
  const float* bo   = (const float*)d_in[12];
  float* out = (float*)d_out;

  char* ws = (char*)d_ws;
  float*          qp  = (float*)(ws + 0);                  //   524,288 fp32 [b][q][c]
  unsigned short* kp  = (unsigned short*)(ws + 524288);    // 2,097,152 bf16 [b][kk][c]
  unsigned short* vt  = (unsigned short*)(ws + 2621440);   // 2,097,152 bf16 [b][h][dd][kk]
  unsigned short* lgb = (unsigned short*)(ws + 4718592);   // 16,777,216 bf16 [b][h][q][kk]
  float*          ctx = (float*)(ws + 21495808);           //   524,288 fp32 [b][q][c]

  proj_row<<<dim3(B_ * Q_), dim3(256), 0, stream>>>(ent, Wq, bq, qp);
  proj_kv<<<dim3(B_ * (KL / 16)), dim3(256), 0, stream>>>(img, Wkv, bkv, kp, vt);
  logits_cpb<<<dim3(B_ * Q_ * 8), dim3(256), 0, stream>>>(qp, kp, rd, W1, b1, W2, b2, lgb);
  sm_pv<<<dim3(B_ * H_ * (Q_ / 16)), dim3(512), 0, stream>>>(lgb, vt, ctx);
  proj_row<<<dim3(B_ * Q_), dim3(256), 0, stream>>>(ctx, Wo, bo, out);
}

// Round 4
// 121.477 us; speedup vs baseline: 2.5584x; 1.3034x over previous
//
#include <hip/hip_runtime.h>
#include <hip/hip_bf16.h>
#include <cstdint>
#include <cstddef>

#define B_  2
#define Q_  256
#define KL  2048
#define D_  256
#define H_  8
#define HD_ 32
#define CH_ 256

typedef unsigned short ushortv4 __attribute__((ext_vector_type(4)));
typedef unsigned short ushortv8 __attribute__((ext_vector_type(8)));
typedef short short8 __attribute__((ext_vector_type(8)));
typedef float f32x4 __attribute__((ext_vector_type(4)));

union U4S8 { unsigned int u[4]; short8 s; };

__device__ __forceinline__ float b2f(unsigned short u) {
  return __uint_as_float(((unsigned int)u) << 16);
}
__device__ __forceinline__ unsigned short f2b_bits(float x) {
  unsigned int u = __float_as_uint(x);
  u += 0x7FFFu + ((u >> 16) & 1u);  // RNE
  return (unsigned short)(u >> 16);
}
__device__ __forceinline__ unsigned int cvt_pk_bf16(float lo, float hi) {
  unsigned int r;
  asm("v_cvt_pk_bf16_f32 %0, %1, %2" : "=v"(r) : "v"(lo), "v"(hi));
  return r;
}
__device__ __forceinline__ short8 pack8(float4 a0, float4 a1) {
  U4S8 u;
  u.u[0] = cvt_pk_bf16(a0.x, a0.y);
  u.u[1] = cvt_pk_bf16(a0.z, a0.w);
  u.u[2] = cvt_pk_bf16(a1.x, a1.y);
  u.u[3] = cvt_pk_bf16(a1.z, a1.w);
  return u.s;
}

// ---------- q projection: qp[row][n] = ent[row][:] . Wq[n][:] + bq[n] (fp32 out)
// grid: (M/16)*(N/64) = 32*4 = 128 blocks; 4 waves, one 16x16 tile each.
__global__ __launch_bounds__(256) void gemm_q(const float* __restrict__ A,
                                              const float* __restrict__ W,
                                              const float* __restrict__ bias,
                                              float* __restrict__ out) {
  int nt = blockIdx.x & 3, mt = blockIdx.x >> 2;
  int t = threadIdx.x, w = t >> 6, l = t & 63;
  int m0 = mt * 16, n0 = nt * 64 + w * 16;
  int r = l & 15, g = l >> 4;
  const float* arow = A + (size_t)(m0 + r) * D_;
  const float* wrow = W + (size_t)(n0 + r) * D_;
  f32x4 acc = {0.f, 0.f, 0.f, 0.f};
#pragma unroll
  for (int s = 0; s < 8; ++s) {
    int kb = s * 32 + g * 8;
    short8 af = pack8(*(const float4*)(arow + kb), *(const float4*)(arow + kb + 4));
    short8 bf = pack8(*(const float4*)(wrow + kb), *(const float4*)(wrow + kb + 4));
    acc = __builtin_amdgcn_mfma_f32_16x16x32_bf16(af, bf, acc, 0, 0, 0);
  }
  int n = n0 + r;
  float bb = bias[n];
#pragma unroll
  for (int rr = 0; rr < 4; ++rr)
    out[(size_t)(m0 + g * 4 + rr) * D_ + n] = acc[rr] + bb;
}

// ---------- kv projection: kp[b][k][c] bf16; vt[b][h][dd][k] bf16 (transposed)
// grid: B * (KL/16) * (512/64) = 2048 blocks
__global__ __launch_bounds__(256) void gemm_kv(const float* __restrict__ img,
                                               const float* __restrict__ Wkv,
                                               const float* __restrict__ bkv,
                                               unsigned short* __restrict__ kp,
                                               unsigned short* __restrict__ vt) {
  int nt = blockIdx.x & 7, mt = (blockIdx.x >> 3) & 127, b = blockIdx.x >> 10;
  int t = threadIdx.x, w = t >> 6, l = t & 63;
  int m0 = mt * 16, n0 = nt * 64 + w * 16;
  int r = l & 15, g = l >> 4;
  const float* arow = img + (size_t)(b * KL + m0 + r) * D_;
  const float* wrow = Wkv + (size_t)(n0 + r) * D_;
  f32x4 acc = {0.f, 0.f, 0.f, 0.f};
#pragma unroll
  for (int s = 0; s < 8; ++s) {
    int kb = s * 32 + g * 8;
    short8 af = pack8(*(const float4*)(arow + kb), *(const float4*)(arow + kb + 4));
    short8 bf = pack8(*(const float4*)(wrow + kb), *(const float4*)(wrow + kb + 4));
    acc = __builtin_amdgcn_mfma_f32_16x16x32_bf16(af, bf, acc, 0, 0, 0);
  }
  int n = n0 + r;
  float bb = bkv[n];
#pragma unroll
  for (int rr = 0; rr < 4; ++rr) acc[rr] += bb;
  if (n < 256) {
    // K out: [b][k][n], scalar bf16 stores (stride 512B over rr)
#pragma unroll
    for (int rr = 0; rr < 4; ++rr)
      kp[((size_t)b * KL + m0 + g * 4 + rr) * D_ + n] = f2b_bits(acc[rr]);
  } else {
    int c = n - 256, h = c >> 5, dd = c & 31;
    ushortv4 p;
#pragma unroll
    for (int rr = 0; rr < 4; ++rr) p[rr] = f2b_bits(acc[rr]);
    *(ushortv4*)(vt + ((size_t)(b * H_ + h) * HD_ + dd) * KL + m0 + g * 4) = p;
  }
}

// ---------- logits = QK^T*scale + CPB (MFMA) + per-chunk softmax stats
// block = (b, q, kc of 256 k); 4 waves x 4 rounds x 16 k.
__global__ __launch_bounds__(256, 4) void logits_cpb(
    const float* __restrict__ qp, const unsigned short* __restrict__ kp,
    const float* __restrict__ rd, const float* __restrict__ W1,
    const float* __restrict__ b1, const float* __restrict__ W2,
    const float* __restrict__ b2, unsigned short* __restrict__ lgb,
    float* __restrict__ stats) {
  int gid = blockIdx.x;
  int q = gid & 255, kc = (gid >> 8) & 7, b = gid >> 11;
  int t = threadIdx.x;
  __shared__ float2 w1p[CH_];
  __shared__ float b1s[CH_];
  __shared__ float qrow[D_];
  __shared__ unsigned short w2b[H_][272];
  __shared__ float b2s[H_];
  __shared__ float wmax[4][8];
  __shared__ float wsum[4][8];
  w1p[t] = make_float2(W1[2 * t], W1[2 * t + 1]);
  b1s[t] = b1[t];
  qrow[t] = qp[(size_t)(b * Q_ + q) * D_ + t];
#pragma unroll
  for (int h = 0; h < H_; ++h) w2b[h][t] = f2b_bits(W2[h * CH_ + t]);
  if (t < H_) b2s[t] = b2[t];
  __syncthreads();

  int l = t & 63, w = t >> 6;
  int hp = l & 15, g = l >> 4, hq = hp & 7;
  int k0 = kc * 256 + w * 64;

  float x[4], y[4];
#pragma unroll
  for (int r = 0; r < 4; ++r) {
    float2 p = *(const float2*)(rd + ((size_t)(b * Q_ + q) * KL + k0 + r * 16 + hp) * 2);
    x[r] = p.x; y[r] = p.y;
  }
  const float scale = 0.17677669529663687f;
  unsigned int qf[4];
#pragma unroll
  for (int m = 0; m < 4; ++m)
    qf[m] = cvt_pk_bf16(qrow[hq * 32 + g * 8 + 2 * m] * scale,
                        qrow[hq * 32 + g * 8 + 2 * m + 1] * scale);

  f32x4 acc[4];
#pragma unroll
  for (int r = 0; r < 4; ++r) acc[r] = (f32x4){0.f, 0.f, 0.f, 0.f};

  const unsigned short* kpb = kp + (size_t)b * KL * D_;
  const unsigned short* kprow[4];
#pragma unroll
  for (int r = 0; r < 4; ++r)
    kprow[r] = kpb + (size_t)(k0 + r * 16 + hp) * D_ + g * 8;

  short8 kf0[4], kf1[4];
#pragma unroll
  for (int r = 0; r < 4; ++r) kf0[r] = *(const short8*)(kprow[r]);

#pragma unroll
  for (int s = 0; s < 8; ++s) {
    if (s < 7) {
#pragma unroll
      for (int r = 0; r < 4; ++r) kf1[r] = *(const short8*)(kprow[r] + (s + 1) * 32);
    }
    int cb = g * 8 + 32 * s;
    float2 wp[8]; float bb[8];
#pragma unroll
    for (int j = 0; j < 8; ++j) { wp[j] = w1p[cb + j]; bb[j] = b1s[cb + j]; }
    short8 w2f = *(const short8*)&w2b[hq][cb];
    U4S8 bq;
#pragma unroll
    for (int m = 0; m < 4; ++m) bq.u[m] = (hp == s) ? qf[m] : 0u;
#pragma unroll
    for (int r = 0; r < 4; ++r) {
      U4S8 az;
#pragma unroll
      for (int m = 0; m < 4; ++m) {
        float z0 = fmaxf(fmaf(x[r], wp[2 * m].x, fmaf(y[r], wp[2 * m].y, bb[2 * m])), 0.f);
        float z1 = fmaxf(fmaf(x[r], wp[2 * m + 1].x, fmaf(y[r], wp[2 * m + 1].y, bb[2 * m + 1])), 0.f);
        az.u[m] = cvt_pk_bf16(z0, z1);
      }
      acc[r] = __builtin_amdgcn_mfma_f32_16x16x32_bf16(az.s, w2f, acc[r], 0, 0, 0);
      acc[r] = __builtin_amdgcn_mfma_f32_16x16x32_bf16(kf0[r], bq.s, acc[r], 0, 0, 0);
    }
#pragma unroll
    for (int r = 0; r < 4; ++r) kf0[r] = kf1[r];
  }

  // epilogue: +b2, chunk stats, packed stores
  int hx = hp & 7;
  float bh = b2s[hx];
  float m = -3.0e38f;
#pragma unroll
  for (int r = 0; r < 4; ++r)
#pragma unroll
    for (int rr = 0; rr < 4; ++rr) {
      acc[r][rr] += bh;
      m = fmaxf(m, acc[r][rr]);
    }
  m = fmaxf(m, __shfl_xor(m, 16));
  m = fmaxf(m, __shfl_xor(m, 32));
  if (l < 8) wmax[w][l] = m;
  __syncthreads();
  float mc = fmaxf(fmaxf(wmax[0][hx], wmax[1][hx]), fmaxf(wmax[2][hx], wmax[3][hx]));
  float ssum = 0.f;
#pragma unroll
  for (int r = 0; r < 4; ++r)
#pragma unroll
    for (int rr = 0; rr < 4; ++rr) ssum += __expf(acc[r][rr] - mc);
  ssum += __shfl_xor(ssum, 16);
  ssum += __shfl_xor(ssum, 32);
  if (l < 8) wsum[w][l] = ssum;

  if (hp < 8) {
    unsigned short* ob = lgb + ((size_t)(b * H_ + hp) * Q_ + q) * KL + k0;
#pragma unroll
    for (int r = 0; r < 4; ++r) {
      ushortv4 pk;
#pragma unroll
      for (int rr = 0; rr < 4; ++rr) pk[rr] = f2b_bits(acc[r][rr]);
      *(ushortv4*)(ob + r * 16 + g * 4) = pk;
    }
  }
  __syncthreads();
  if (t < 8) {
    float mm = fmaxf(fmaxf(wmax[0][t], wmax[1][t]), fmaxf(wmax[2][t], wmax[3][t]));
    float ss = wsum[0][t] + wsum[1][t] + wsum[2][t] + wsum[3][t];
    *(float2*)(stats + (((size_t)(b * H_ + t) * Q_ + q) * 8 + kc) * 2) =
        make_float2(mm, ss);
  }
}

// ---------- fused softmax + PV (single pass over lgb, uses chunk stats)
// block = (b,h, 16 q-rows), 512 threads (8 waves); writes ctxb bf16
__global__ __launch_bounds__(512) void sm_pv(const unsigned short* __restrict__ lgb,
                                             const float* __restrict__ stats,
                                             const unsigned short* __restrict__ vt,
                                             unsigned short* __restrict__ ctxb) {
  int gid = blockIdx.x;
  int qt = gid & 15, bh = gid >> 4;
  int t = threadIdx.x;
  __shared__ float Ms[16], Ss[16];
  __shared__ float pacc[8][16][33];

  if (t < 16) {
    const float* sp = stats + ((size_t)bh * Q_ + qt * 16 + t) * 16;
    float M = -3.0e38f;
#pragma unroll
    for (int kc = 0; kc < 8; ++kc) M = fmaxf(M, sp[2 * kc]);
    float S = 0.f;
#pragma unroll
    for (int kc = 0; kc < 8; ++kc) S += sp[2 * kc + 1] * __expf(sp[2 * kc] - M);
    Ms[t] = M;
    Ss[t] = 1.0f / S;
  }
  __syncthreads();

  int l = t & 63, w = t >> 6;
  int qq = l & 15, g = l >> 4;
  float mq = Ms[qq];
  const unsigned short* lr2 = lgb + ((size_t)bh * Q_ + qt * 16 + qq) * KL + w * 256 + g * 8;
  const unsigned short* vb0 = vt + ((size_t)bh * HD_ + qq) * KL + w * 256 + g * 8;
  const unsigned short* vb1 = vb0 + (size_t)16 * KL;
  f32x4 a0 = {0.f, 0.f, 0.f, 0.f}, a1 = {0.f, 0.f, 0.f, 0.f};
#pragma unroll
  for (int step = 0; step < 8; ++step) {
    ushortv8 rawp = *(const ushortv8*)(lr2 + step * 32);
    U4S8 pa;
#pragma unroll
    for (int mI = 0; mI < 4; ++mI) {
      float p0 = __expf(b2f(rawp[2 * mI]) - mq);
      float p1 = __expf(b2f(rawp[2 * mI + 1]) - mq);
      pa.u[mI] = cvt_pk_bf16(p0, p1);
    }
    short8 v0 = *(const short8*)(vb0 + step * 32);
    short8 v1 = *(const short8*)(vb1 + step * 32);
    a0 = __builtin_amdgcn_mfma_f32_16x16x32_bf16(pa.s, v0, a0, 0, 0, 0);
    a1 = __builtin_amdgcn_mfma_f32_16x16x32_bf16(pa.s, v1, a1, 0, 0, 0);
  }
#pragma unroll
  for (int rr = 0; rr < 4; ++rr) {
    pacc[w][g * 4 + rr][qq] = a0[rr];
    pacc[w][g * 4 + rr][qq + 16] = a1[rr];
  }
  __syncthreads();

  int qo = t >> 5, dd = t & 31;
  float sum = 0.f;
#pragma unroll
  for (int wv = 0; wv < 8; ++wv) sum += pacc[wv][qo][dd];
  sum *= Ss[qo];
  int b = bh >> 3, h = bh & 7;
  ctxb[((size_t)b * Q_ + qt * 16 + qo) * D_ + h * HD_ + dd] = f2b_bits(sum);
}

// ---------- out projection: out = ctxb(bf16) @ Wo^T + bo (fp32 out)
__global__ __launch_bounds__(256) void gemm_o(const unsigned short* __restrict__ A,
                                              const float* __restrict__ W,
                                              const float* __restrict__ bias,
                                              float* __restrict__ out) {
  int nt = blockIdx.x & 3, mt = blockIdx.x >> 2;
  int t = threadIdx.x, w = t >> 6, l = t & 63;
  int m0 = mt * 16, n0 = nt * 64 + w * 16;
  int r = l & 15, g = l >> 4;
  const unsigned short* arow = A + (size_t)(m0 + r) * D_;
  const float* wrow = W + (size_t)(n0 + r) * D_;
  f32x4 acc = {0.f, 0.f, 0.f, 0.f};
#pragma unroll
  for (int s = 0; s < 8; ++s) {
    int kb = s * 32 + g * 8;
    short8 af = *(const short8*)(arow + kb);
    short8 bf = pack8(*(const float4*)(wrow + kb), *(const float4*)(wrow + kb + 4));
    acc = __builtin_amdgcn_mfma_f32_16x16x32_bf16(af, bf, acc, 0, 0, 0);
  }
  int n = n0 + r;
  float bb = bias[n];
#pragma unroll
  for (int rr = 0; rr < 4; ++rr)
    out[(size_t)(m0 + g * 4 + rr) * D_ + n] = acc[rr] + bb;
}

extern "C" void kernel_launch(void* const* d_in, const int* in_sizes, int n_in,
                              void* d_out, int out_size, void* d_ws, size_t ws_size,
                              hipStream_t stream) {
  const float* ent  = (const float*)d_in[0];
  const float* img  = (const float*)d_in[1];
  const float* rd   = (const float*)d_in[2];
  const float* Wq   = (const float*)d_in[3];
  const float* bq   = (const float*)d_in[4];
  const float* Wkv  = (const float*)d_in[5];
  const float* bkv  = (const float*)d_in[6];
  const float* W1   = (const float*)d_in[7];
  const float* b1   = (const float*)d_in[8];
  const float* W2   = (const float*)d_in[9];
  const float* b2   = (const float*)d_in[10];
  const float* Wo   = (const float*)d_in[11];
  const float* bo   = (const float*)d_in[12];
  float* out = (float*)d_out;

  char* ws = (char*)d_ws;
  float*          qp    = (float*)(ws + 0);                  //   524,288 fp32 [b][q][c]
  unsigned short* kp    = (unsigned short*)(ws + 524288);    // 2,097,152 bf16 [b][kk][c]
  unsigned short* vt    = (unsigned short*)(ws + 2621440);   // 2,097,152 bf16 [b][h][dd][kk]
  unsigned short* lgb   = (unsigned short*)(ws + 4718592);   // 16,777,216 bf16 [b][h][q][kk]
  float*          stats = (float*)(ws + 21495808);           //   262,144 float2 [b][h][q][kc]
  unsigned short* ctxb  = (unsigned short*)(ws + 21757952);  //   262,144 bf16 [b][q][c]

  gemm_q<<<dim3(128), dim3(256), 0, stream>>>(ent, Wq, bq, qp);
  gemm_kv<<<dim3(2048), dim3(256), 0, stream>>>(img, Wkv, bkv, kp, vt);
  logits_cpb<<<dim3(B_ * Q_ * 8), dim3(256), 0, stream>>>(qp, kp, rd, W1, b1, W2, b2, lgb, stats);
  sm_pv<<<dim3(B_ * H_ * (Q_ / 16)), dim3(512), 0, stream>>>(lgb, stats, vt, ctxb);
  gemm_o<<<dim3(128), dim3(256), 0, stream>>>(ctxb, Wo, bo, out);
}